// Round 10
// baseline (288.600 us; speedup 1.0000x reference)
//
#include <hip/hip_runtime.h>
#include <hip/hip_fp16.h>
#include <type_traits>

#define D 128

// ---- parallel scan stage 1: per-1024-chunk sums ---------------------------

__global__ __launch_bounds__(256) void bsum_kernel(const int* __restrict__ deg,
                                                   int* __restrict__ bsum) {
  __shared__ int ws[4];
  int i0 = blockIdx.x * 1024 + threadIdx.x * 4;
  int4 v = *reinterpret_cast<const int4*>(deg + i0);   // zero-padded
  int s = v.x + v.y + v.z + v.w;
  #pragma unroll
  for (int off = 32; off; off >>= 1) s += __shfl_down(s, off);
  if ((threadIdx.x & 63) == 0) ws[threadIdx.x >> 6] = s;
  __syncthreads();
  if (threadIdx.x == 0) bsum[blockIdx.x] = ws[0] + ws[1] + ws[2] + ws[3];
}

// ---- parallel scan stage 2: exclusive offsets + fused dinv ----------------

__global__ __launch_bounds__(256) void scan_kernel(const int* __restrict__ deg,
                                                   const int* __restrict__ bsum,
                                                   int* __restrict__ offsets,
                                                   float* __restrict__ dinv,
                                                   int N, int E) {
  __shared__ int ts[256];
  int b = blockIdx.x;
  int base = 0;
  for (int t = 0; t < b; ++t) base += bsum[t];

  int i0 = b * 1024 + threadIdx.x * 4;
  int4 v = *reinterpret_cast<const int4*>(deg + i0);
  int t4 = v.x + v.y + v.z + v.w;
  ts[threadIdx.x] = t4;
  __syncthreads();
  #pragma unroll
  for (int off = 1; off < 256; off <<= 1) {
    int u = (threadIdx.x >= off) ? ts[threadIdx.x - off] : 0;
    __syncthreads();
    ts[threadIdx.x] += u;
    __syncthreads();
  }
  int run = base + ts[threadIdx.x] - t4;

  int dd[4] = {v.x, v.y, v.z, v.w};
  #pragma unroll
  for (int k = 0; k < 4; ++k) {
    int i = i0 + k;
    if (i < N) {
      offsets[i] = run;
      dinv[i] = rsqrtf(1.0f + (float)dd[k]);
    }
    run += dd[k];
  }
  if (b == 0 && threadIdx.x == 0) offsets[N] = E;
}

// ---- atomic-free placement, 4 edges/thread; pack {src:17, norm_q15:15} ----

__global__ __launch_bounds__(256) void place_kernel(const int* __restrict__ src,
                                                    const int* __restrict__ dst,
                                                    const int* __restrict__ rank,
                                                    const int* __restrict__ offsets,
                                                    const float* __restrict__ dinv,
                                                    unsigned int* __restrict__ csr, int E) {
  int t = blockIdx.x * 256 + threadIdx.x;
  int e0 = t * 4;
  if (e0 + 4 <= E) {
    int4 s4 = *reinterpret_cast<const int4*>(src + e0);
    int4 d4 = *reinterpret_cast<const int4*>(dst + e0);
    int4 r4 = *reinterpret_cast<const int4*>(rank + e0);
    int ss[4] = {s4.x, s4.y, s4.z, s4.w};
    int dd[4] = {d4.x, d4.y, d4.z, d4.w};
    int rr[4] = {r4.x, r4.y, r4.z, r4.w};
    int pos[4];
    float nm[4];
    #pragma unroll
    for (int k = 0; k < 4; ++k) pos[k] = offsets[dd[k]] + rr[k];
    #pragma unroll
    for (int k = 0; k < 4; ++k) nm[k] = dinv[ss[k]] * dinv[dd[k]];
    #pragma unroll
    for (int k = 0; k < 4; ++k) {
      unsigned int q = (unsigned int)__float2int_rn(nm[k] * 32767.0f);
      csr[pos[k]] = ((unsigned int)ss[k] << 15) | q;
    }
  } else {
    for (int e = e0; e < E; ++e) {
      int s = src[e];
      int d = dst[e];
      int pos = offsets[d] + rank[e];
      float nm = dinv[s] * dinv[d];
      unsigned int q = (unsigned int)__float2int_rn(nm * 32767.0f);
      csr[pos] = ((unsigned int)s << 15) | q;
    }
  }
}

// ---- GEMM device body: H[N,128](fp16) = X[N,128] @ W[128,128] -------------

template <typename TI>
__device__ __forceinline__ void gemm_body(const TI* __restrict__ X,
                                          const float* __restrict__ W,
                                          __half* __restrict__ H, int N, int bid) {
  __shared__ float xs[32 * D];
  int row0 = bid * 32;
  if constexpr (std::is_same<TI, float>::value) {
    #pragma unroll
    for (int jj = 0; jj < 4; ++jj) {
      int f4 = threadIdx.x + jj * 256;
      int r = f4 >> 5;
      float4 v = make_float4(0.f, 0.f, 0.f, 0.f);
      if (row0 + r < N) v = *reinterpret_cast<const float4*>(X + (size_t)row0 * D + (size_t)f4 * 4);
      *reinterpret_cast<float4*>(xs + f4 * 4) = v;
    }
  } else {
    #pragma unroll
    for (int jj = 0; jj < 2; ++jj) {
      int g8 = threadIdx.x + jj * 256;
      int r = g8 >> 4;
      uint4 raw = make_uint4(0u, 0u, 0u, 0u);
      if (row0 + r < N)
        raw = *reinterpret_cast<const uint4*>((const __half*)X + (size_t)row0 * D + (size_t)g8 * 8);
      const __half2* hp = reinterpret_cast<const __half2*>(&raw);
      float* dst8 = xs + (size_t)g8 * 8;
      #pragma unroll
      for (int k = 0; k < 4; ++k) {
        float2 f = __half22float2(hp[k]);
        dst8[k * 2] = f.x;
        dst8[k * 2 + 1] = f.y;
      }
    }
  }
  __syncthreads();

  int tx = threadIdx.x & 63;
  int ty = threadIdx.x >> 6;
  int c0 = tx * 2;
  float2 acc[8];
  #pragma unroll
  for (int r = 0; r < 8; ++r) acc[r] = make_float2(0.f, 0.f);
  const float* xbase = xs + ty * 8 * D;

  for (int k = 0; k < D; k += 4) {
    float2 w0 = *reinterpret_cast<const float2*>(W + (size_t)(k + 0) * D + c0);
    float2 w1 = *reinterpret_cast<const float2*>(W + (size_t)(k + 1) * D + c0);
    float2 w2 = *reinterpret_cast<const float2*>(W + (size_t)(k + 2) * D + c0);
    float2 w3 = *reinterpret_cast<const float2*>(W + (size_t)(k + 3) * D + c0);
    #pragma unroll
    for (int r = 0; r < 8; ++r) {
      float4 xv = *reinterpret_cast<const float4*>(xbase + r * D + k);
      acc[r].x = fmaf(xv.x, w0.x, acc[r].x); acc[r].y = fmaf(xv.x, w0.y, acc[r].y);
      acc[r].x = fmaf(xv.y, w1.x, acc[r].x); acc[r].y = fmaf(xv.y, w1.y, acc[r].y);
      acc[r].x = fmaf(xv.z, w2.x, acc[r].x); acc[r].y = fmaf(xv.z, w2.y, acc[r].y);
      acc[r].x = fmaf(xv.w, w3.x, acc[r].x); acc[r].y = fmaf(xv.w, w3.y, acc[r].y);
    }
  }

  #pragma unroll
  for (int r = 0; r < 8; ++r) {
    int row = row0 + ty * 8 + r;
    if (row < N)
      *reinterpret_cast<__half2*>(H + (size_t)row * D + c0) = __floats2half2_rn(acc[r].x, acc[r].y);
  }
}

// ---- fused: gemm1 (blocks [0,GB)) || degree histogram (blocks [GB,...)) ---

__global__ __launch_bounds__(256) void fused_gemm_deg_kernel(
    const float* __restrict__ X, const float* __restrict__ W,
    __half* __restrict__ H, int N, int GB,
    const int* __restrict__ dst, int* __restrict__ deg,
    int* __restrict__ rank, int E) {
  if ((int)blockIdx.x < GB) {
    gemm_body<float>(X, W, H, N, blockIdx.x);
  } else {
    int e = (blockIdx.x - GB) * 256 + threadIdx.x;
    if (e < E) rank[e] = atomicAdd(&deg[dst[e]], 1);
  }
}

// ---- standalone gemm (layer 2) --------------------------------------------

__global__ __launch_bounds__(256) void gemm_h_kernel(const __half* __restrict__ X,
                                                     const float* __restrict__ W,
                                                     __half* __restrict__ H, int N) {
  gemm_body<__half>(X, W, H, N, blockIdx.x);
}

// ---- Aggregation: one wave per dst node -----------------------------------
// 4 edge-groups (g = lane>>4) x 16 feature-lanes (l = lane&15, 8 halves each).
// Unroll-4 per group: up to 16 row-gathers in flight per wave.

template <int DO_RELU, typename TO>
__global__ __launch_bounds__(256) void agg_kernel(const __half* __restrict__ H,
                                                  const int* __restrict__ offsets,
                                                  const unsigned int* __restrict__ csr,
                                                  const float* __restrict__ dinv,
                                                  const float* __restrict__ bias,
                                                  TO* __restrict__ out, int N) {
  int n = blockIdx.x * 4 + (threadIdx.x >> 6);
  if (n >= N) return;
  int lane = threadIdx.x & 63;
  int g = lane >> 4;
  int l = lane & 15;

  int beg = offsets[n];
  int end = offsets[n + 1];

  float acc[8];
  #pragma unroll
  for (int k = 0; k < 8; ++k) acc[k] = 0.f;

  const __half* Hl = H + l * 8;

  int j = beg + g;
  for (; j + 12 < end; j += 16) {
    unsigned int p0 = csr[j];
    unsigned int p1 = csr[j + 4];
    unsigned int p2 = csr[j + 8];
    unsigned int p3 = csr[j + 12];
    float m0 = (float)(p0 & 0x7fffu) * (1.0f / 32767.0f);
    float m1 = (float)(p1 & 0x7fffu) * (1.0f / 32767.0f);
    float m2 = (float)(p2 & 0x7fffu) * (1.0f / 32767.0f);
    float m3 = (float)(p3 & 0x7fffu) * (1.0f / 32767.0f);
    uint4 r0 = *reinterpret_cast<const uint4*>(Hl + (size_t)(p0 >> 15) * D);
    uint4 r1 = *reinterpret_cast<const uint4*>(Hl + (size_t)(p1 >> 15) * D);
    uint4 r2 = *reinterpret_cast<const uint4*>(Hl + (size_t)(p2 >> 15) * D);
    uint4 r3 = *reinterpret_cast<const uint4*>(Hl + (size_t)(p3 >> 15) * D);
    const __half2* h0 = reinterpret_cast<const __half2*>(&r0);
    const __half2* h1 = reinterpret_cast<const __half2*>(&r1);
    const __half2* h2 = reinterpret_cast<const __half2*>(&r2);
    const __half2* h3 = reinterpret_cast<const __half2*>(&r3);
    #pragma unroll
    for (int k = 0; k < 4; ++k) {
      float2 f0 = __half22float2(h0[k]);
      float2 f1 = __half22float2(h1[k]);
      float2 f2 = __half22float2(h2[k]);
      float2 f3 = __half22float2(h3[k]);
      acc[2 * k]     = fmaf(f0.x, m0, acc[2 * k]);
      acc[2 * k + 1] = fmaf(f0.y, m0, acc[2 * k + 1]);
      acc[2 * k]     = fmaf(f1.x, m1, acc[2 * k]);
      acc[2 * k + 1] = fmaf(f1.y, m1, acc[2 * k + 1]);
      acc[2 * k]     = fmaf(f2.x, m2, acc[2 * k]);
      acc[2 * k + 1] = fmaf(f2.y, m2, acc[2 * k + 1]);
      acc[2 * k]     = fmaf(f3.x, m3, acc[2 * k]);
      acc[2 * k + 1] = fmaf(f3.y, m3, acc[2 * k + 1]);
    }
  }
  for (; j < end; j += 4) {
    unsigned int p0 = csr[j];
    float m0 = (float)(p0 & 0x7fffu) * (1.0f / 32767.0f);
    uint4 r0 = *reinterpret_cast<const uint4*>(Hl + (size_t)(p0 >> 15) * D);
    const __half2* h0 = reinterpret_cast<const __half2*>(&r0);
    #pragma unroll
    for (int k = 0; k < 4; ++k) {
      float2 f0 = __half22float2(h0[k]);
      acc[2 * k]     = fmaf(f0.x, m0, acc[2 * k]);
      acc[2 * k + 1] = fmaf(f0.y, m0, acc[2 * k + 1]);
    }
  }

  #pragma unroll
  for (int k = 0; k < 8; ++k) {
    acc[k] += __shfl_xor(acc[k], 16);
    acc[k] += __shfl_xor(acc[k], 32);
  }

  if (g == 0) {
    float di = dinv[n];
    float dii = di * di;
    uint4 rs = *reinterpret_cast<const uint4*>(Hl + (size_t)n * D);
    const __half2* hs = reinterpret_cast<const __half2*>(&rs);
    float4 bv0 = *reinterpret_cast<const float4*>(bias + l * 8);
    float4 bv1 = *reinterpret_cast<const float4*>(bias + l * 8 + 4);
    float v[8];
    #pragma unroll
    for (int k = 0; k < 4; ++k) {
      float2 f = __half22float2(hs[k]);
      v[2 * k]     = fmaf(f.x, dii, acc[2 * k]);
      v[2 * k + 1] = fmaf(f.y, dii, acc[2 * k + 1]);
    }
    v[0] += bv0.x; v[1] += bv0.y; v[2] += bv0.z; v[3] += bv0.w;
    v[4] += bv1.x; v[5] += bv1.y; v[6] += bv1.z; v[7] += bv1.w;
    if (DO_RELU) {
      #pragma unroll
      for (int k = 0; k < 8; ++k) v[k] = fmaxf(v[k], 0.f);
    }
    if constexpr (std::is_same<TO, float>::value) {
      float4 o0 = make_float4(v[0], v[1], v[2], v[3]);
      float4 o1 = make_float4(v[4], v[5], v[6], v[7]);
      *reinterpret_cast<float4*>(out + (size_t)n * D + l * 8) = o0;
      *reinterpret_cast<float4*>(out + (size_t)n * D + l * 8 + 4) = o1;
    } else {
      uint4 pk;
      __half2 q0 = __floats2half2_rn(v[0], v[1]);
      __half2 q1 = __floats2half2_rn(v[2], v[3]);
      __half2 q2 = __floats2half2_rn(v[4], v[5]);
      __half2 q3 = __floats2half2_rn(v[6], v[7]);
      pk.x = *reinterpret_cast<unsigned int*>(&q0);
      pk.y = *reinterpret_cast<unsigned int*>(&q1);
      pk.z = *reinterpret_cast<unsigned int*>(&q2);
      pk.w = *reinterpret_cast<unsigned int*>(&q3);
      *reinterpret_cast<uint4*>((__half*)out + (size_t)n * D + l * 8) = pk;
    }
  }
}

// ---- launch ---------------------------------------------------------------

extern "C" void kernel_launch(void* const* d_in, const int* in_sizes, int n_in,
                              void* d_out, int out_size, void* d_ws, size_t ws_size,
                              hipStream_t stream) {
  const float* x  = (const float*)d_in[0];
  const int* edge = (const int*)d_in[1];
  const float* W1 = (const float*)d_in[2];
  const float* b1 = (const float*)d_in[3];
  const float* W2 = (const float*)d_in[4];
  const float* b2 = (const float*)d_in[5];
  const int N = in_sizes[0] / D;   // 50000
  const int E = in_sizes[1] / 2;   // 1.6M
  const int* srcp = edge;
  const int* dstp = edge + E;
  float* out = (float*)d_out;

  const int NP = (N + 1023) & ~1023;
  const int SB = NP / 1024;

  auto align = [](size_t v) { return (v + 255) & ~(size_t)255; };
  char* ws = (char*)d_ws;
  size_t o = 0;
  int*   deg     = (int*)(ws + o);             o += align((size_t)NP * 4);
  int*   bsum    = (int*)(ws + o);             o += align((size_t)SB * 4);
  int*   offsets = (int*)(ws + o);             o += align((size_t)(N + 1) * 4);
  int*   rank    = (int*)(ws + o);             o += align((size_t)E * 4);
  float* dinv    = (float*)(ws + o);           o += align((size_t)N * 4);
  unsigned int* csr = (unsigned int*)(ws + o); o += align((size_t)E * 4);
  __half* Hh     = (__half*)(ws + o);          o += align((size_t)N * D * 2);
  __half* h1h    = (__half*)(ws + o);          o += align((size_t)N * D * 2);

  int gemm_blocks = (N + 31) / 32;
  int deg_blocks  = (E + 255) / 256;
  int agg_blocks  = (N + 3) / 4;

  // memset deg, then fused {gemm1 || deg histogram}
  hipMemsetAsync(deg, 0, (size_t)NP * 4, stream);
  fused_gemm_deg_kernel<<<gemm_blocks + deg_blocks, 256, 0, stream>>>(
      x, W1, Hh, N, gemm_blocks, dstp, deg, rank, E);

  // scan -> offsets/dinv, then placement
  bsum_kernel<<<SB, 256, 0, stream>>>(deg, bsum);
  scan_kernel<<<SB, 256, 0, stream>>>(deg, bsum, offsets, dinv, N, E);
  int pl_threads = (E + 3) / 4;
  place_kernel<<<(pl_threads + 255) / 256, 256, 0, stream>>>(srcp, dstp, rank, offsets, dinv, csr, E);

  // layer 1 aggregation: h1 = relu(A @ (x@W1) + b1)
  agg_kernel<1, __half><<<agg_blocks, 256, 0, stream>>>(Hh, offsets, csr, dinv, b1, h1h, N);

  // layer 2: z = A @ (h1@W2) + b2 -> f32 d_out
  gemm_h_kernel<<<gemm_blocks, 256, 0, stream>>>(h1h, W2, Hh, N);
  agg_kernel<0, float><<<agg_blocks, 256, 0, stream>>>(Hh, offsets, csr, dinv, b2, out, N);
}

// Round 11
// 281.270 us; speedup vs baseline: 1.0261x; 1.0261x over previous
//
#include <hip/hip_runtime.h>
#include <hip/hip_fp16.h>
#include <type_traits>

#define D 128

// ---- degree histogram + per-edge rank (1 edge/thread — best measured) -----
// Atomic-RMW wall ~25 G/s is throughput-bound: neither more counters (r8)
// nor more in-flight atomics/thread (r9) nor co-residency with gemm (r10)
// improves it. Keep the simplest form.

__global__ __launch_bounds__(256) void deg_kernel(const int* __restrict__ dst,
                                                  int* __restrict__ deg,
                                                  int* __restrict__ rank, int E) {
  int e = blockIdx.x * 256 + threadIdx.x;
  if (e < E) rank[e] = atomicAdd(&deg[dst[e]], 1);
}

// ---- parallel scan stage 1: per-1024-chunk sums ---------------------------

__global__ __launch_bounds__(256) void bsum_kernel(const int* __restrict__ deg,
                                                   int* __restrict__ bsum) {
  __shared__ int ws[4];
  int i0 = blockIdx.x * 1024 + threadIdx.x * 4;
  int4 v = *reinterpret_cast<const int4*>(deg + i0);   // zero-padded
  int s = v.x + v.y + v.z + v.w;
  #pragma unroll
  for (int off = 32; off; off >>= 1) s += __shfl_down(s, off);
  if ((threadIdx.x & 63) == 0) ws[threadIdx.x >> 6] = s;
  __syncthreads();
  if (threadIdx.x == 0) bsum[blockIdx.x] = ws[0] + ws[1] + ws[2] + ws[3];
}

// ---- parallel scan stage 2: exclusive offsets + fused dinv ----------------

__global__ __launch_bounds__(256) void scan_kernel(const int* __restrict__ deg,
                                                   const int* __restrict__ bsum,
                                                   int* __restrict__ offsets,
                                                   float* __restrict__ dinv,
                                                   int N, int E) {
  __shared__ int ts[256];
  int b = blockIdx.x;
  int base = 0;
  for (int t = 0; t < b; ++t) base += bsum[t];

  int i0 = b * 1024 + threadIdx.x * 4;
  int4 v = *reinterpret_cast<const int4*>(deg + i0);
  int t4 = v.x + v.y + v.z + v.w;
  ts[threadIdx.x] = t4;
  __syncthreads();
  #pragma unroll
  for (int off = 1; off < 256; off <<= 1) {
    int u = (threadIdx.x >= off) ? ts[threadIdx.x - off] : 0;
    __syncthreads();
    ts[threadIdx.x] += u;
    __syncthreads();
  }
  int run = base + ts[threadIdx.x] - t4;

  int dd[4] = {v.x, v.y, v.z, v.w};
  #pragma unroll
  for (int k = 0; k < 4; ++k) {
    int i = i0 + k;
    if (i < N) {
      offsets[i] = run;
      dinv[i] = rsqrtf(1.0f + (float)dd[k]);
    }
    run += dd[k];
  }
  if (b == 0 && threadIdx.x == 0) offsets[N] = E;
}

// ---- atomic-free placement, 4 edges/thread; pack {src:17, norm_q15:15} ----

__global__ __launch_bounds__(256) void place_kernel(const int* __restrict__ src,
                                                    const int* __restrict__ dst,
                                                    const int* __restrict__ rank,
                                                    const int* __restrict__ offsets,
                                                    const float* __restrict__ dinv,
                                                    unsigned int* __restrict__ csr, int E) {
  int t = blockIdx.x * 256 + threadIdx.x;
  int e0 = t * 4;
  if (e0 + 4 <= E) {
    int4 s4 = *reinterpret_cast<const int4*>(src + e0);
    int4 d4 = *reinterpret_cast<const int4*>(dst + e0);
    int4 r4 = *reinterpret_cast<const int4*>(rank + e0);
    int ss[4] = {s4.x, s4.y, s4.z, s4.w};
    int dd[4] = {d4.x, d4.y, d4.z, d4.w};
    int rr[4] = {r4.x, r4.y, r4.z, r4.w};
    int pos[4];
    float nm[4];
    #pragma unroll
    for (int k = 0; k < 4; ++k) pos[k] = offsets[dd[k]] + rr[k];
    #pragma unroll
    for (int k = 0; k < 4; ++k) nm[k] = dinv[ss[k]] * dinv[dd[k]];
    #pragma unroll
    for (int k = 0; k < 4; ++k) {
      unsigned int q = (unsigned int)__float2int_rn(nm[k] * 32767.0f);
      csr[pos[k]] = ((unsigned int)ss[k] << 15) | q;
    }
  } else {
    for (int e = e0; e < E; ++e) {
      int s = src[e];
      int d = dst[e];
      int pos = offsets[d] + rank[e];
      float nm = dinv[s] * dinv[d];
      unsigned int q = (unsigned int)__float2int_rn(nm * 32767.0f);
      csr[pos] = ((unsigned int)s << 15) | q;
    }
  }
}

// ---- GEMM: H[N,128](fp16) = X[N,128] @ W[128,128] -------------------------

template <typename TI>
__global__ __launch_bounds__(256) void gemm_kernel(const TI* __restrict__ X,
                                                   const float* __restrict__ W,
                                                   __half* __restrict__ H, int N) {
  __shared__ float xs[32 * D];
  int row0 = blockIdx.x * 32;
  if constexpr (std::is_same<TI, float>::value) {
    #pragma unroll
    for (int jj = 0; jj < 4; ++jj) {
      int f4 = threadIdx.x + jj * 256;
      int r = f4 >> 5;
      float4 v = make_float4(0.f, 0.f, 0.f, 0.f);
      if (row0 + r < N) v = *reinterpret_cast<const float4*>(X + (size_t)row0 * D + (size_t)f4 * 4);
      *reinterpret_cast<float4*>(xs + f4 * 4) = v;
    }
  } else {
    #pragma unroll
    for (int jj = 0; jj < 2; ++jj) {
      int g8 = threadIdx.x + jj * 256;
      int r = g8 >> 4;
      uint4 raw = make_uint4(0u, 0u, 0u, 0u);
      if (row0 + r < N)
        raw = *reinterpret_cast<const uint4*>((const __half*)X + (size_t)row0 * D + (size_t)g8 * 8);
      const __half2* hp = reinterpret_cast<const __half2*>(&raw);
      float* dst8 = xs + (size_t)g8 * 8;
      #pragma unroll
      for (int k = 0; k < 4; ++k) {
        float2 f = __half22float2(hp[k]);
        dst8[k * 2] = f.x;
        dst8[k * 2 + 1] = f.y;
      }
    }
  }
  __syncthreads();

  int tx = threadIdx.x & 63;
  int ty = threadIdx.x >> 6;
  int c0 = tx * 2;
  float2 acc[8];
  #pragma unroll
  for (int r = 0; r < 8; ++r) acc[r] = make_float2(0.f, 0.f);
  const float* xbase = xs + ty * 8 * D;

  for (int k = 0; k < D; k += 4) {
    float2 w0 = *reinterpret_cast<const float2*>(W + (size_t)(k + 0) * D + c0);
    float2 w1 = *reinterpret_cast<const float2*>(W + (size_t)(k + 1) * D + c0);
    float2 w2 = *reinterpret_cast<const float2*>(W + (size_t)(k + 2) * D + c0);
    float2 w3 = *reinterpret_cast<const float2*>(W + (size_t)(k + 3) * D + c0);
    #pragma unroll
    for (int r = 0; r < 8; ++r) {
      float4 xv = *reinterpret_cast<const float4*>(xbase + r * D + k);
      acc[r].x = fmaf(xv.x, w0.x, acc[r].x); acc[r].y = fmaf(xv.x, w0.y, acc[r].y);
      acc[r].x = fmaf(xv.y, w1.x, acc[r].x); acc[r].y = fmaf(xv.y, w1.y, acc[r].y);
      acc[r].x = fmaf(xv.z, w2.x, acc[r].x); acc[r].y = fmaf(xv.z, w2.y, acc[r].y);
      acc[r].x = fmaf(xv.w, w3.x, acc[r].x); acc[r].y = fmaf(xv.w, w3.y, acc[r].y);
    }
  }

  #pragma unroll
  for (int r = 0; r < 8; ++r) {
    int row = row0 + ty * 8 + r;
    if (row < N)
      *reinterpret_cast<__half2*>(H + (size_t)row * D + c0) = __floats2half2_rn(acc[r].x, acc[r].y);
  }
}

// ---- Aggregation: one wave per dst node -----------------------------------
// 4 edge-groups (g = lane>>4) x 16 feature-lanes (l = lane&15, 8 halves each).
// Unroll-4 per group: up to 16 row-gathers in flight per wave.

template <int DO_RELU, typename TO>
__global__ __launch_bounds__(256) void agg_kernel(const __half* __restrict__ H,
                                                  const int* __restrict__ offsets,
                                                  const unsigned int* __restrict__ csr,
                                                  const float* __restrict__ dinv,
                                                  const float* __restrict__ bias,
                                                  TO* __restrict__ out, int N) {
  int n = blockIdx.x * 4 + (threadIdx.x >> 6);
  if (n >= N) return;
  int lane = threadIdx.x & 63;
  int g = lane >> 4;
  int l = lane & 15;

  int beg = offsets[n];
  int end = offsets[n + 1];

  float acc[8];
  #pragma unroll
  for (int k = 0; k < 8; ++k) acc[k] = 0.f;

  const __half* Hl = H + l * 8;

  int j = beg + g;
  for (; j + 12 < end; j += 16) {
    unsigned int p0 = csr[j];
    unsigned int p1 = csr[j + 4];
    unsigned int p2 = csr[j + 8];
    unsigned int p3 = csr[j + 12];
    float m0 = (float)(p0 & 0x7fffu) * (1.0f / 32767.0f);
    float m1 = (float)(p1 & 0x7fffu) * (1.0f / 32767.0f);
    float m2 = (float)(p2 & 0x7fffu) * (1.0f / 32767.0f);
    float m3 = (float)(p3 & 0x7fffu) * (1.0f / 32767.0f);
    uint4 r0 = *reinterpret_cast<const uint4*>(Hl + (size_t)(p0 >> 15) * D);
    uint4 r1 = *reinterpret_cast<const uint4*>(Hl + (size_t)(p1 >> 15) * D);
    uint4 r2 = *reinterpret_cast<const uint4*>(Hl + (size_t)(p2 >> 15) * D);
    uint4 r3 = *reinterpret_cast<const uint4*>(Hl + (size_t)(p3 >> 15) * D);
    const __half2* h0 = reinterpret_cast<const __half2*>(&r0);
    const __half2* h1 = reinterpret_cast<const __half2*>(&r1);
    const __half2* h2 = reinterpret_cast<const __half2*>(&r2);
    const __half2* h3 = reinterpret_cast<const __half2*>(&r3);
    #pragma unroll
    for (int k = 0; k < 4; ++k) {
      float2 f0 = __half22float2(h0[k]);
      float2 f1 = __half22float2(h1[k]);
      float2 f2 = __half22float2(h2[k]);
      float2 f3 = __half22float2(h3[k]);
      acc[2 * k]     = fmaf(f0.x, m0, acc[2 * k]);
      acc[2 * k + 1] = fmaf(f0.y, m0, acc[2 * k + 1]);
      acc[2 * k]     = fmaf(f1.x, m1, acc[2 * k]);
      acc[2 * k + 1] = fmaf(f1.y, m1, acc[2 * k + 1]);
      acc[2 * k]     = fmaf(f2.x, m2, acc[2 * k]);
      acc[2 * k + 1] = fmaf(f2.y, m2, acc[2 * k + 1]);
      acc[2 * k]     = fmaf(f3.x, m3, acc[2 * k]);
      acc[2 * k + 1] = fmaf(f3.y, m3, acc[2 * k + 1]);
    }
  }
  for (; j < end; j += 4) {
    unsigned int p0 = csr[j];
    float m0 = (float)(p0 & 0x7fffu) * (1.0f / 32767.0f);
    uint4 r0 = *reinterpret_cast<const uint4*>(Hl + (size_t)(p0 >> 15) * D);
    const __half2* h0 = reinterpret_cast<const __half2*>(&r0);
    #pragma unroll
    for (int k = 0; k < 4; ++k) {
      float2 f0 = __half22float2(h0[k]);
      acc[2 * k]     = fmaf(f0.x, m0, acc[2 * k]);
      acc[2 * k + 1] = fmaf(f0.y, m0, acc[2 * k + 1]);
    }
  }

  #pragma unroll
  for (int k = 0; k < 8; ++k) {
    acc[k] += __shfl_xor(acc[k], 16);
    acc[k] += __shfl_xor(acc[k], 32);
  }

  if (g == 0) {
    float di = dinv[n];
    float dii = di * di;
    uint4 rs = *reinterpret_cast<const uint4*>(Hl + (size_t)n * D);
    const __half2* hs = reinterpret_cast<const __half2*>(&rs);
    float4 bv0 = *reinterpret_cast<const float4*>(bias + l * 8);
    float4 bv1 = *reinterpret_cast<const float4*>(bias + l * 8 + 4);
    float v[8];
    #pragma unroll
    for (int k = 0; k < 4; ++k) {
      float2 f = __half22float2(hs[k]);
      v[2 * k]     = fmaf(f.x, dii, acc[2 * k]);
      v[2 * k + 1] = fmaf(f.y, dii, acc[2 * k + 1]);
    }
    v[0] += bv0.x; v[1] += bv0.y; v[2] += bv0.z; v[3] += bv0.w;
    v[4] += bv1.x; v[5] += bv1.y; v[6] += bv1.z; v[7] += bv1.w;
    if (DO_RELU) {
      #pragma unroll
      for (int k = 0; k < 8; ++k) v[k] = fmaxf(v[k], 0.f);
    }
    if constexpr (std::is_same<TO, float>::value) {
      float4 o0 = make_float4(v[0], v[1], v[2], v[3]);
      float4 o1 = make_float4(v[4], v[5], v[6], v[7]);
      *reinterpret_cast<float4*>(out + (size_t)n * D + l * 8) = o0;
      *reinterpret_cast<float4*>(out + (size_t)n * D + l * 8 + 4) = o1;
    } else {
      uint4 pk;
      __half2 q0 = __floats2half2_rn(v[0], v[1]);
      __half2 q1 = __floats2half2_rn(v[2], v[3]);
      __half2 q2 = __floats2half2_rn(v[4], v[5]);
      __half2 q3 = __floats2half2_rn(v[6], v[7]);
      pk.x = *reinterpret_cast<unsigned int*>(&q0);
      pk.y = *reinterpret_cast<unsigned int*>(&q1);
      pk.z = *reinterpret_cast<unsigned int*>(&q2);
      pk.w = *reinterpret_cast<unsigned int*>(&q3);
      *reinterpret_cast<uint4*>((__half*)out + (size_t)n * D + l * 8) = pk;
    }
  }
}

// ---- launch ---------------------------------------------------------------

extern "C" void kernel_launch(void* const* d_in, const int* in_sizes, int n_in,
                              void* d_out, int out_size, void* d_ws, size_t ws_size,
                              hipStream_t stream) {
  const float* x  = (const float*)d_in[0];
  const int* edge = (const int*)d_in[1];
  const float* W1 = (const float*)d_in[2];
  const float* b1 = (const float*)d_in[3];
  const float* W2 = (const float*)d_in[4];
  const float* b2 = (const float*)d_in[5];
  const int N = in_sizes[0] / D;   // 50000
  const int E = in_sizes[1] / 2;   // 1.6M
  const int* srcp = edge;
  const int* dstp = edge + E;
  float* out = (float*)d_out;

  const int NP = (N + 1023) & ~1023;
  const int SB = NP / 1024;

  auto align = [](size_t v) { return (v + 255) & ~(size_t)255; };
  char* ws = (char*)d_ws;
  size_t o = 0;
  int*   deg     = (int*)(ws + o);             o += align((size_t)NP * 4);
  int*   bsum    = (int*)(ws + o);             o += align((size_t)SB * 4);
  int*   offsets = (int*)(ws + o);             o += align((size_t)(N + 1) * 4);
  int*   rank    = (int*)(ws + o);             o += align((size_t)E * 4);
  float* dinv    = (float*)(ws + o);           o += align((size_t)N * 4);
  unsigned int* csr = (unsigned int*)(ws + o); o += align((size_t)E * 4);
  __half* Hh     = (__half*)(ws + o);          o += align((size_t)N * D * 2);
  __half* h1h    = (__half*)(ws + o);          o += align((size_t)N * D * 2);

  int gemm_blocks = (N + 31) / 32;
  int agg_blocks  = (N + 3) / 4;

  // CSR build
  hipMemsetAsync(deg, 0, (size_t)NP * 4, stream);
  deg_kernel<<<(E + 255) / 256, 256, 0, stream>>>(dstp, deg, rank, E);
  bsum_kernel<<<SB, 256, 0, stream>>>(deg, bsum);
  scan_kernel<<<SB, 256, 0, stream>>>(deg, bsum, offsets, dinv, N, E);
  int pl_threads = (E + 3) / 4;
  place_kernel<<<(pl_threads + 255) / 256, 256, 0, stream>>>(srcp, dstp, rank, offsets, dinv, csr, E);

  // layer 1: h1 = relu(A @ (x@W1) + b1)   (fp16 intermediates)
  gemm_kernel<float><<<gemm_blocks, 256, 0, stream>>>(x, W1, Hh, N);
  agg_kernel<1, __half><<<agg_blocks, 256, 0, stream>>>(Hh, offsets, csr, dinv, b1, h1h, N);

  // layer 2: z = A @ (h1@W2) + b2 -> f32 d_out
  gemm_kernel<__half><<<gemm_blocks, 256, 0, stream>>>(h1h, W2, Hh, N);
  agg_kernel<0, float><<<agg_blocks, 256, 0, stream>>>(Hh, offsets, csr, dinv, b2, out, N);
}

// Round 12
// 241.190 us; speedup vs baseline: 1.1966x; 1.1662x over previous
//
#include <hip/hip_runtime.h>
#include <hip/hip_fp16.h>
#include <type_traits>

#define D 128
#define NI 128          // edge chunks
#define NR 25000        // nodes per range-block (2 ranges cover N=50000); 100KB LDS

// ---- Pass A: per-(chunk,range) LDS histogram -> c[i][n] -------------------

__global__ __launch_bounds__(1024) void histA_kernel(const int* __restrict__ dst,
                                                     int* __restrict__ c,
                                                     int E, int N, int CH) {
  __shared__ int cnt[NR];
  int i = blockIdx.x, r = blockIdx.y;
  int base = r * NR;
  int kmax = min(NR, N - base);
  for (int k = threadIdx.x; k < kmax; k += 1024) cnt[k] = 0;
  __syncthreads();
  int e0 = i * CH, e1 = min(e0 + CH, E);
  for (int e = e0 + (int)threadIdx.x; e < e1; e += 1024) {
    unsigned dr = (unsigned)(dst[e] - base);
    if (dr < (unsigned)kmax) atomicAdd(&cnt[dr], 1);
  }
  __syncthreads();
  int* ci = c + (size_t)i * N + base;
  for (int k = threadIdx.x; k < kmax; k += 1024) ci[k] = cnt[k];
}

// ---- Pass B: per-node exclusive prefix over chunks (in place) + deg -------

__global__ __launch_bounds__(256) void histB_kernel(int* __restrict__ c,
                                                    int* __restrict__ deg, int N) {
  int n = blockIdx.x * 256 + threadIdx.x;
  if (n >= N) return;
  int run = 0;
  #pragma unroll 8
  for (int i = 0; i < NI; ++i) {
    size_t idx = (size_t)i * N + n;
    int v = c[idx];
    c[idx] = run;
    run += v;
  }
  deg[n] = run;
}

// ---- parallel scan stage 1: per-1024-chunk sums ---------------------------

__global__ __launch_bounds__(256) void bsum_kernel(const int* __restrict__ deg,
                                                   int* __restrict__ bsum) {
  __shared__ int ws[4];
  int i0 = blockIdx.x * 1024 + threadIdx.x * 4;
  int4 v = *reinterpret_cast<const int4*>(deg + i0);   // zero-padded
  int s = v.x + v.y + v.z + v.w;
  #pragma unroll
  for (int off = 32; off; off >>= 1) s += __shfl_down(s, off);
  if ((threadIdx.x & 63) == 0) ws[threadIdx.x >> 6] = s;
  __syncthreads();
  if (threadIdx.x == 0) bsum[blockIdx.x] = ws[0] + ws[1] + ws[2] + ws[3];
}

// ---- parallel scan stage 2: exclusive offsets + fused dinv ----------------

__global__ __launch_bounds__(256) void scan_kernel(const int* __restrict__ deg,
                                                   const int* __restrict__ bsum,
                                                   int* __restrict__ offsets,
                                                   float* __restrict__ dinv,
                                                   int N, int E) {
  __shared__ int ts[256];
  int b = blockIdx.x;
  int base = 0;
  for (int t = 0; t < b; ++t) base += bsum[t];

  int i0 = b * 1024 + threadIdx.x * 4;
  int4 v = *reinterpret_cast<const int4*>(deg + i0);
  int t4 = v.x + v.y + v.z + v.w;
  ts[threadIdx.x] = t4;
  __syncthreads();
  #pragma unroll
  for (int off = 1; off < 256; off <<= 1) {
    int u = (threadIdx.x >= off) ? ts[threadIdx.x - off] : 0;
    __syncthreads();
    ts[threadIdx.x] += u;
    __syncthreads();
  }
  int run = base + ts[threadIdx.x] - t4;

  int dd[4] = {v.x, v.y, v.z, v.w};
  #pragma unroll
  for (int k = 0; k < 4; ++k) {
    int i = i0 + k;
    if (i < N) {
      offsets[i] = run;
      dinv[i] = rsqrtf(1.0f + (float)dd[k]);
    }
    run += dd[k];
  }
  if (b == 0 && threadIdx.x == 0) offsets[N] = E;
}

// ---- Pass C: placement via LDS counters (zero global atomics) -------------
// cnt[d] starts at offsets[d] + chunk-prefix c[i][d]; LDS atomicAdd hands out
// globally-unique CSR slots. Pack {src:17, norm_q15:15} into 4 B.

__global__ __launch_bounds__(1024) void placeC_kernel(const int* __restrict__ src,
                                                      const int* __restrict__ dst,
                                                      const int* __restrict__ c,
                                                      const int* __restrict__ offsets,
                                                      const float* __restrict__ dinv,
                                                      unsigned int* __restrict__ csr,
                                                      int E, int N, int CH) {
  __shared__ int cnt[NR];
  int i = blockIdx.x, r = blockIdx.y;
  int base = r * NR;
  int kmax = min(NR, N - base);
  const int* ci = c + (size_t)i * N + base;
  for (int k = threadIdx.x; k < kmax; k += 1024) cnt[k] = offsets[base + k] + ci[k];
  __syncthreads();
  int e0 = i * CH, e1 = min(e0 + CH, E);
  for (int e = e0 + (int)threadIdx.x; e < e1; e += 1024) {
    int d = dst[e];
    unsigned dr = (unsigned)(d - base);
    if (dr < (unsigned)kmax) {
      int pos = atomicAdd(&cnt[dr], 1);
      int s = src[e];
      float nm = dinv[s] * dinv[d];
      unsigned int q = (unsigned int)__float2int_rn(nm * 32767.0f);
      csr[pos] = ((unsigned int)s << 15) | q;
    }
  }
}

// ---- GEMM: H[N,128](fp16) = X[N,128] @ W[128,128] -------------------------

template <typename TI>
__global__ __launch_bounds__(256) void gemm_kernel(const TI* __restrict__ X,
                                                   const float* __restrict__ W,
                                                   __half* __restrict__ H, int N) {
  __shared__ float xs[32 * D];
  int row0 = blockIdx.x * 32;
  if constexpr (std::is_same<TI, float>::value) {
    #pragma unroll
    for (int jj = 0; jj < 4; ++jj) {
      int f4 = threadIdx.x + jj * 256;
      int r = f4 >> 5;
      float4 v = make_float4(0.f, 0.f, 0.f, 0.f);
      if (row0 + r < N) v = *reinterpret_cast<const float4*>(X + (size_t)row0 * D + (size_t)f4 * 4);
      *reinterpret_cast<float4*>(xs + f4 * 4) = v;
    }
  } else {
    #pragma unroll
    for (int jj = 0; jj < 2; ++jj) {
      int g8 = threadIdx.x + jj * 256;
      int r = g8 >> 4;
      uint4 raw = make_uint4(0u, 0u, 0u, 0u);
      if (row0 + r < N)
        raw = *reinterpret_cast<const uint4*>((const __half*)X + (size_t)row0 * D + (size_t)g8 * 8);
      const __half2* hp = reinterpret_cast<const __half2*>(&raw);
      float* dst8 = xs + (size_t)g8 * 8;
      #pragma unroll
      for (int k = 0; k < 4; ++k) {
        float2 f = __half22float2(hp[k]);
        dst8[k * 2] = f.x;
        dst8[k * 2 + 1] = f.y;
      }
    }
  }
  __syncthreads();

  int tx = threadIdx.x & 63;
  int ty = threadIdx.x >> 6;
  int c0 = tx * 2;
  float2 acc[8];
  #pragma unroll
  for (int r = 0; r < 8; ++r) acc[r] = make_float2(0.f, 0.f);
  const float* xbase = xs + ty * 8 * D;

  for (int k = 0; k < D; k += 4) {
    float2 w0 = *reinterpret_cast<const float2*>(W + (size_t)(k + 0) * D + c0);
    float2 w1 = *reinterpret_cast<const float2*>(W + (size_t)(k + 1) * D + c0);
    float2 w2 = *reinterpret_cast<const float2*>(W + (size_t)(k + 2) * D + c0);
    float2 w3 = *reinterpret_cast<const float2*>(W + (size_t)(k + 3) * D + c0);
    #pragma unroll
    for (int r = 0; r < 8; ++r) {
      float4 xv = *reinterpret_cast<const float4*>(xbase + r * D + k);
      acc[r].x = fmaf(xv.x, w0.x, acc[r].x); acc[r].y = fmaf(xv.x, w0.y, acc[r].y);
      acc[r].x = fmaf(xv.y, w1.x, acc[r].x); acc[r].y = fmaf(xv.y, w1.y, acc[r].y);
      acc[r].x = fmaf(xv.z, w2.x, acc[r].x); acc[r].y = fmaf(xv.z, w2.y, acc[r].y);
      acc[r].x = fmaf(xv.w, w3.x, acc[r].x); acc[r].y = fmaf(xv.w, w3.y, acc[r].y);
    }
  }

  #pragma unroll
  for (int r = 0; r < 8; ++r) {
    int row = row0 + ty * 8 + r;
    if (row < N)
      *reinterpret_cast<__half2*>(H + (size_t)row * D + c0) = __floats2half2_rn(acc[r].x, acc[r].y);
  }
}

// ---- Aggregation: one wave per dst node -----------------------------------
// 4 edge-groups (g = lane>>4) x 16 feature-lanes (l = lane&15, 8 halves each).
// Unroll-4 per group: up to 16 row-gathers in flight per wave.

template <int DO_RELU, typename TO>
__global__ __launch_bounds__(256) void agg_kernel(const __half* __restrict__ H,
                                                  const int* __restrict__ offsets,
                                                  const unsigned int* __restrict__ csr,
                                                  const float* __restrict__ dinv,
                                                  const float* __restrict__ bias,
                                                  TO* __restrict__ out, int N) {
  int n = blockIdx.x * 4 + (threadIdx.x >> 6);
  if (n >= N) return;
  int lane = threadIdx.x & 63;
  int g = lane >> 4;
  int l = lane & 15;

  int beg = offsets[n];
  int end = offsets[n + 1];

  float acc[8];
  #pragma unroll
  for (int k = 0; k < 8; ++k) acc[k] = 0.f;

  const __half* Hl = H + l * 8;

  int j = beg + g;
  for (; j + 12 < end; j += 16) {
    unsigned int p0 = csr[j];
    unsigned int p1 = csr[j + 4];
    unsigned int p2 = csr[j + 8];
    unsigned int p3 = csr[j + 12];
    float m0 = (float)(p0 & 0x7fffu) * (1.0f / 32767.0f);
    float m1 = (float)(p1 & 0x7fffu) * (1.0f / 32767.0f);
    float m2 = (float)(p2 & 0x7fffu) * (1.0f / 32767.0f);
    float m3 = (float)(p3 & 0x7fffu) * (1.0f / 32767.0f);
    uint4 r0 = *reinterpret_cast<const uint4*>(Hl + (size_t)(p0 >> 15) * D);
    uint4 r1 = *reinterpret_cast<const uint4*>(Hl + (size_t)(p1 >> 15) * D);
    uint4 r2 = *reinterpret_cast<const uint4*>(Hl + (size_t)(p2 >> 15) * D);
    uint4 r3 = *reinterpret_cast<const uint4*>(Hl + (size_t)(p3 >> 15) * D);
    const __half2* h0 = reinterpret_cast<const __half2*>(&r0);
    const __half2* h1 = reinterpret_cast<const __half2*>(&r1);
    const __half2* h2 = reinterpret_cast<const __half2*>(&r2);
    const __half2* h3 = reinterpret_cast<const __half2*>(&r3);
    #pragma unroll
    for (int k = 0; k < 4; ++k) {
      float2 f0 = __half22float2(h0[k]);
      float2 f1 = __half22float2(h1[k]);
      float2 f2 = __half22float2(h2[k]);
      float2 f3 = __half22float2(h3[k]);
      acc[2 * k]     = fmaf(f0.x, m0, acc[2 * k]);
      acc[2 * k + 1] = fmaf(f0.y, m0, acc[2 * k + 1]);
      acc[2 * k]     = fmaf(f1.x, m1, acc[2 * k]);
      acc[2 * k + 1] = fmaf(f1.y, m1, acc[2 * k + 1]);
      acc[2 * k]     = fmaf(f2.x, m2, acc[2 * k]);
      acc[2 * k + 1] = fmaf(f2.y, m2, acc[2 * k + 1]);
      acc[2 * k]     = fmaf(f3.x, m3, acc[2 * k]);
      acc[2 * k + 1] = fmaf(f3.y, m3, acc[2 * k + 1]);
    }
  }
  for (; j < end; j += 4) {
    unsigned int p0 = csr[j];
    float m0 = (float)(p0 & 0x7fffu) * (1.0f / 32767.0f);
    uint4 r0 = *reinterpret_cast<const uint4*>(Hl + (size_t)(p0 >> 15) * D);
    const __half2* h0 = reinterpret_cast<const __half2*>(&r0);
    #pragma unroll
    for (int k = 0; k < 4; ++k) {
      float2 f0 = __half22float2(h0[k]);
      acc[2 * k]     = fmaf(f0.x, m0, acc[2 * k]);
      acc[2 * k + 1] = fmaf(f0.y, m0, acc[2 * k + 1]);
    }
  }

  #pragma unroll
  for (int k = 0; k < 8; ++k) {
    acc[k] += __shfl_xor(acc[k], 16);
    acc[k] += __shfl_xor(acc[k], 32);
  }

  if (g == 0) {
    float di = dinv[n];
    float dii = di * di;
    uint4 rs = *reinterpret_cast<const uint4*>(Hl + (size_t)n * D);
    const __half2* hs = reinterpret_cast<const __half2*>(&rs);
    float4 bv0 = *reinterpret_cast<const float4*>(bias + l * 8);
    float4 bv1 = *reinterpret_cast<const float4*>(bias + l * 8 + 4);
    float v[8];
    #pragma unroll
    for (int k = 0; k < 4; ++k) {
      float2 f = __half22float2(hs[k]);
      v[2 * k]     = fmaf(f.x, dii, acc[2 * k]);
      v[2 * k + 1] = fmaf(f.y, dii, acc[2 * k + 1]);
    }
    v[0] += bv0.x; v[1] += bv0.y; v[2] += bv0.z; v[3] += bv0.w;
    v[4] += bv1.x; v[5] += bv1.y; v[6] += bv1.z; v[7] += bv1.w;
    if (DO_RELU) {
      #pragma unroll
      for (int k = 0; k < 8; ++k) v[k] = fmaxf(v[k], 0.f);
    }
    if constexpr (std::is_same<TO, float>::value) {
      float4 o0 = make_float4(v[0], v[1], v[2], v[3]);
      float4 o1 = make_float4(v[4], v[5], v[6], v[7]);
      *reinterpret_cast<float4*>(out + (size_t)n * D + l * 8) = o0;
      *reinterpret_cast<float4*>(out + (size_t)n * D + l * 8 + 4) = o1;
    } else {
      uint4 pk;
      __half2 q0 = __floats2half2_rn(v[0], v[1]);
      __half2 q1 = __floats2half2_rn(v[2], v[3]);
      __half2 q2 = __floats2half2_rn(v[4], v[5]);
      __half2 q3 = __floats2half2_rn(v[6], v[7]);
      pk.x = *reinterpret_cast<unsigned int*>(&q0);
      pk.y = *reinterpret_cast<unsigned int*>(&q1);
      pk.z = *reinterpret_cast<unsigned int*>(&q2);
      pk.w = *reinterpret_cast<unsigned int*>(&q3);
      *reinterpret_cast<uint4*>((__half*)out + (size_t)n * D + l * 8) = pk;
    }
  }
}

// ---- launch ---------------------------------------------------------------

extern "C" void kernel_launch(void* const* d_in, const int* in_sizes, int n_in,
                              void* d_out, int out_size, void* d_ws, size_t ws_size,
                              hipStream_t stream) {
  const float* x  = (const float*)d_in[0];
  const int* edge = (const int*)d_in[1];
  const float* W1 = (const float*)d_in[2];
  const float* b1 = (const float*)d_in[3];
  const float* W2 = (const float*)d_in[4];
  const float* b2 = (const float*)d_in[5];
  const int N = in_sizes[0] / D;   // 50000
  const int E = in_sizes[1] / 2;   // 1.6M
  const int* srcp = edge;
  const int* dstp = edge + E;
  float* out = (float*)d_out;

  const int NP = (N + 1023) & ~1023;
  const int SB = NP / 1024;
  const int CH = (E + NI - 1) / NI;
  const int NRB = (N + NR - 1) / NR;            // node-range blocks (2)

  auto align = [](size_t v) { return (v + 255) & ~(size_t)255; };
  char* ws = (char*)d_ws;
  size_t o = 0;
  int*   deg     = (int*)(ws + o);             o += align((size_t)NP * 4);
  int*   bsum    = (int*)(ws + o);             o += align((size_t)SB * 4);
  int*   offsets = (int*)(ws + o);             o += align((size_t)(N + 1) * 4);
  float* dinv    = (float*)(ws + o);           o += align((size_t)N * 4);
  int*   c       = (int*)(ws + o);             o += align((size_t)NI * N * 4);   // 25.6MB
  unsigned int* csr = (unsigned int*)(ws + o); o += align((size_t)E * 4);
  __half* Hh     = (__half*)(ws + o);          o += align((size_t)N * D * 2);
  __half* h1h    = (__half*)(ws + o);          o += align((size_t)N * D * 2);

  int gemm_blocks = (N + 31) / 32;
  int agg_blocks  = (N + 3) / 4;

  // CSR build — zero global atomics
  hipMemsetAsync(deg, 0, (size_t)NP * 4, stream);
  histA_kernel<<<dim3(NI, NRB), 1024, 0, stream>>>(dstp, c, E, N, CH);
  histB_kernel<<<(N + 255) / 256, 256, 0, stream>>>(c, deg, N);
  bsum_kernel<<<SB, 256, 0, stream>>>(deg, bsum);
  scan_kernel<<<SB, 256, 0, stream>>>(deg, bsum, offsets, dinv, N, E);
  placeC_kernel<<<dim3(NI, NRB), 1024, 0, stream>>>(srcp, dstp, c, offsets, dinv, csr, E, N, CH);

  // layer 1: h1 = relu(A @ (x@W1) + b1)   (fp16 intermediates)
  gemm_kernel<float><<<gemm_blocks, 256, 0, stream>>>(x, W1, Hh, N);
  agg_kernel<1, __half><<<agg_blocks, 256, 0, stream>>>(Hh, offsets, csr, dinv, b1, h1h, N);

  // layer 2: z = A @ (h1@W2) + b2 -> f32 d_out
  gemm_kernel<__half><<<gemm_blocks, 256, 0, stream>>>(h1h, W2, Hh, N);
  agg_kernel<0, float><<<agg_blocks, 256, 0, stream>>>(Hh, offsets, csr, dinv, b2, out, N);
}

// Round 13
// 232.861 us; speedup vs baseline: 1.2394x; 1.0358x over previous
//
#include <hip/hip_runtime.h>
#include <hip/hip_fp16.h>
#include <type_traits>

#define D 128
#define NI 128          // edge chunks
#define NR 25000        // nodes per range-block (2 ranges cover N=50000); 100KB LDS

using half8 = __attribute__((ext_vector_type(8))) _Float16;
using f32x4 = __attribute__((ext_vector_type(4))) float;

// ---- W prep: transpose + cvt to fp16:  Wt[col][k] = W[k][col] -------------

__global__ __launch_bounds__(256) void wprep_kernel(const float* __restrict__ W1,
                                                    const float* __restrict__ W2,
                                                    __half* __restrict__ Wt1,
                                                    __half* __restrict__ Wt2) {
  const float* W = blockIdx.x ? W2 : W1;
  __half* Wt = blockIdx.x ? Wt2 : Wt1;
  for (int idx = threadIdx.x; idx < D * D; idx += 256) {
    int c = idx & 127, k = idx >> 7;
    Wt[c * D + k] = __float2half(W[k * D + c]);
  }
}

// ---- Pass A: per-(chunk,range) LDS histogram -> c[i][n] (u16) -------------

__global__ __launch_bounds__(1024) void histA_kernel(const int* __restrict__ dst,
                                                     unsigned short* __restrict__ c,
                                                     int E, int N, int CH) {
  __shared__ int cnt[NR];
  int i = blockIdx.x, r = blockIdx.y;
  int base = r * NR;
  int kmax = min(NR, N - base);
  for (int k = threadIdx.x; k < kmax; k += 1024) cnt[k] = 0;
  __syncthreads();
  int e0 = i * CH, e1 = min(e0 + CH, E);
  for (int e = e0 + (int)threadIdx.x; e < e1; e += 1024) {
    unsigned dr = (unsigned)(dst[e] - base);
    if (dr < (unsigned)kmax) atomicAdd(&cnt[dr], 1);
  }
  __syncthreads();
  unsigned short* ci = c + (size_t)i * N + base;
  for (int k = threadIdx.x; k < kmax; k += 1024) ci[k] = (unsigned short)cnt[k];
}

// ---- Pass B: per-node exclusive prefix over chunks (in place) + deg -------

__global__ __launch_bounds__(256) void histB_kernel(unsigned short* __restrict__ c,
                                                    int* __restrict__ deg, int N) {
  int n = blockIdx.x * 256 + threadIdx.x;
  if (n >= N) return;
  int run = 0;
  #pragma unroll 8
  for (int i = 0; i < NI; ++i) {
    size_t idx = (size_t)i * N + n;
    int v = c[idx];
    c[idx] = (unsigned short)run;
    run += v;
  }
  deg[n] = run;
}

// ---- parallel scan stage 1: per-1024-chunk sums ---------------------------

__global__ __launch_bounds__(256) void bsum_kernel(const int* __restrict__ deg,
                                                   int* __restrict__ bsum) {
  __shared__ int ws[4];
  int i0 = blockIdx.x * 1024 + threadIdx.x * 4;
  int4 v = *reinterpret_cast<const int4*>(deg + i0);   // zero-padded
  int s = v.x + v.y + v.z + v.w;
  #pragma unroll
  for (int off = 32; off; off >>= 1) s += __shfl_down(s, off);
  if ((threadIdx.x & 63) == 0) ws[threadIdx.x >> 6] = s;
  __syncthreads();
  if (threadIdx.x == 0) bsum[blockIdx.x] = ws[0] + ws[1] + ws[2] + ws[3];
}

// ---- parallel scan stage 2: exclusive offsets + fused dinv ----------------

__global__ __launch_bounds__(256) void scan_kernel(const int* __restrict__ deg,
                                                   const int* __restrict__ bsum,
                                                   int* __restrict__ offsets,
                                                   float* __restrict__ dinv,
                                                   int N, int E) {
  __shared__ int ts[256];
  int b = blockIdx.x;
  int base = 0;
  for (int t = 0; t < b; ++t) base += bsum[t];

  int i0 = b * 1024 + threadIdx.x * 4;
  int4 v = *reinterpret_cast<const int4*>(deg + i0);
  int t4 = v.x + v.y + v.z + v.w;
  ts[threadIdx.x] = t4;
  __syncthreads();
  #pragma unroll
  for (int off = 1; off < 256; off <<= 1) {
    int u = (threadIdx.x >= off) ? ts[threadIdx.x - off] : 0;
    __syncthreads();
    ts[threadIdx.x] += u;
    __syncthreads();
  }
  int run = base + ts[threadIdx.x] - t4;

  int dd[4] = {v.x, v.y, v.z, v.w};
  #pragma unroll
  for (int k = 0; k < 4; ++k) {
    int i = i0 + k;
    if (i < N) {
      offsets[i] = run;
      dinv[i] = rsqrtf(1.0f + (float)dd[k]);
    }
    run += dd[k];
  }
  if (b == 0 && threadIdx.x == 0) offsets[N] = E;
}

// ---- Pass C: placement via LDS counters (zero global atomics) -------------

__global__ __launch_bounds__(1024) void placeC_kernel(const int* __restrict__ src,
                                                      const int* __restrict__ dst,
                                                      const unsigned short* __restrict__ c,
                                                      const int* __restrict__ offsets,
                                                      const float* __restrict__ dinv,
                                                      unsigned int* __restrict__ csr,
                                                      int E, int N, int CH) {
  __shared__ int cnt[NR];
  int i = blockIdx.x, r = blockIdx.y;
  int base = r * NR;
  int kmax = min(NR, N - base);
  const unsigned short* ci = c + (size_t)i * N + base;
  for (int k = threadIdx.x; k < kmax; k += 1024) cnt[k] = offsets[base + k] + (int)ci[k];
  __syncthreads();
  int e0 = i * CH, e1 = min(e0 + CH, E);
  for (int e = e0 + (int)threadIdx.x; e < e1; e += 1024) {
    int d = dst[e];
    unsigned dr = (unsigned)(d - base);
    if (dr < (unsigned)kmax) {
      int pos = atomicAdd(&cnt[dr], 1);
      int s = src[e];
      float nm = dinv[s] * dinv[d];
      unsigned int q = (unsigned int)__float2int_rn(nm * 32767.0f);
      csr[pos] = ((unsigned int)s << 15) | q;
    }
  }
}

// ---- MFMA GEMM: H[N,128](fp16) = X[N,128] @ W[128,128] --------------------
// 4 waves/block, 16 rows/wave. A-frags from global (cvt if f32); B-frags from
// transposed fp16 Wt (32KB, L1-resident). 32 mfma_f32_16x16x32_f16 per wave.

template <typename TI>
__global__ __launch_bounds__(256) void gemm_mfma_kernel(const TI* __restrict__ X,
                                                        const __half* __restrict__ Wt,
                                                        __half* __restrict__ H, int N) {
  int wid = threadIdx.x >> 6;
  int l = threadIdx.x & 63;
  int row0w = blockIdx.x * 64 + wid * 16;
  int arow = row0w + (l & 15);
  int k0 = (l >> 4) * 8;

  half8 A[4];
  #pragma unroll
  for (int kt = 0; kt < 4; ++kt) {
    half8 a = {};
    if (arow < N) {
      if constexpr (std::is_same<TI, float>::value) {
        const float* p = X + (size_t)arow * D + kt * 32 + k0;
        float4 u = *reinterpret_cast<const float4*>(p);
        float4 v = *reinterpret_cast<const float4*>(p + 4);
        a[0] = (_Float16)u.x; a[1] = (_Float16)u.y;
        a[2] = (_Float16)u.z; a[3] = (_Float16)u.w;
        a[4] = (_Float16)v.x; a[5] = (_Float16)v.y;
        a[6] = (_Float16)v.z; a[7] = (_Float16)v.w;
      } else {
        a = *reinterpret_cast<const half8*>((const __half*)X + (size_t)arow * D + kt * 32 + k0);
      }
    }
    A[kt] = a;
  }

  int wrow = row0w + (l >> 4) * 4;
  int col = l & 15;
  #pragma unroll
  for (int ct = 0; ct < 8; ++ct) {
    f32x4 acc = {0.f, 0.f, 0.f, 0.f};
    #pragma unroll
    for (int kt = 0; kt < 4; ++kt) {
      half8 b = *reinterpret_cast<const half8*>(Wt + (size_t)(ct * 16 + col) * D + kt * 32 + k0);
      acc = __builtin_amdgcn_mfma_f32_16x16x32_f16(A[kt], b, acc, 0, 0, 0);
    }
    #pragma unroll
    for (int r = 0; r < 4; ++r) {
      int row = wrow + r;
      if (row < N) H[(size_t)row * D + ct * 16 + col] = __float2half(acc[r]);
    }
  }
}

// ---- Aggregation: one wave per dst node (unchanged, r11/r12 best) ---------

template <int DO_RELU, typename TO>
__global__ __launch_bounds__(256) void agg_kernel(const __half* __restrict__ H,
                                                  const int* __restrict__ offsets,
                                                  const unsigned int* __restrict__ csr,
                                                  const float* __restrict__ dinv,
                                                  const float* __restrict__ bias,
                                                  TO* __restrict__ out, int N) {
  int n = blockIdx.x * 4 + (threadIdx.x >> 6);
  if (n >= N) return;
  int lane = threadIdx.x & 63;
  int g = lane >> 4;
  int l = lane & 15;

  int beg = offsets[n];
  int end = offsets[n + 1];

  float acc[8];
  #pragma unroll
  for (int k = 0; k < 8; ++k) acc[k] = 0.f;

  const __half* Hl = H + l * 8;

  int j = beg + g;
  for (; j + 12 < end; j += 16) {
    unsigned int p0 = csr[j];
    unsigned int p1 = csr[j + 4];
    unsigned int p2 = csr[j + 8];
    unsigned int p3 = csr[j + 12];
    float m0 = (float)(p0 & 0x7fffu) * (1.0f / 32767.0f);
    float m1 = (float)(p1 & 0x7fffu) * (1.0f / 32767.0f);
    float m2 = (float)(p2 & 0x7fffu) * (1.0f / 32767.0f);
    float m3 = (float)(p3 & 0x7fffu) * (1.0f / 32767.0f);
    uint4 r0 = *reinterpret_cast<const uint4*>(Hl + (size_t)(p0 >> 15) * D);
    uint4 r1 = *reinterpret_cast<const uint4*>(Hl + (size_t)(p1 >> 15) * D);
    uint4 r2 = *reinterpret_cast<const uint4*>(Hl + (size_t)(p2 >> 15) * D);
    uint4 r3 = *reinterpret_cast<const uint4*>(Hl + (size_t)(p3 >> 15) * D);
    const __half2* h0 = reinterpret_cast<const __half2*>(&r0);
    const __half2* h1 = reinterpret_cast<const __half2*>(&r1);
    const __half2* h2 = reinterpret_cast<const __half2*>(&r2);
    const __half2* h3 = reinterpret_cast<const __half2*>(&r3);
    #pragma unroll
    for (int k = 0; k < 4; ++k) {
      float2 f0 = __half22float2(h0[k]);
      float2 f1 = __half22float2(h1[k]);
      float2 f2 = __half22float2(h2[k]);
      float2 f3 = __half22float2(h3[k]);
      acc[2 * k]     = fmaf(f0.x, m0, acc[2 * k]);
      acc[2 * k + 1] = fmaf(f0.y, m0, acc[2 * k + 1]);
      acc[2 * k]     = fmaf(f1.x, m1, acc[2 * k]);
      acc[2 * k + 1] = fmaf(f1.y, m1, acc[2 * k + 1]);
      acc[2 * k]     = fmaf(f2.x, m2, acc[2 * k]);
      acc[2 * k + 1] = fmaf(f2.y, m2, acc[2 * k + 1]);
      acc[2 * k]     = fmaf(f3.x, m3, acc[2 * k]);
      acc[2 * k + 1] = fmaf(f3.y, m3, acc[2 * k + 1]);
    }
  }
  for (; j < end; j += 4) {
    unsigned int p0 = csr[j];
    float m0 = (float)(p0 & 0x7fffu) * (1.0f / 32767.0f);
    uint4 r0 = *reinterpret_cast<const uint4*>(Hl + (size_t)(p0 >> 15) * D);
    const __half2* h0 = reinterpret_cast<const __half2*>(&r0);
    #pragma unroll
    for (int k = 0; k < 4; ++k) {
      float2 f0 = __half22float2(h0[k]);
      acc[2 * k]     = fmaf(f0.x, m0, acc[2 * k]);
      acc[2 * k + 1] = fmaf(f0.y, m0, acc[2 * k + 1]);
    }
  }

  #pragma unroll
  for (int k = 0; k < 8; ++k) {
    acc[k] += __shfl_xor(acc[k], 16);
    acc[k] += __shfl_xor(acc[k], 32);
  }

  if (g == 0) {
    float di = dinv[n];
    float dii = di * di;
    uint4 rs = *reinterpret_cast<const uint4*>(Hl + (size_t)n * D);
    const __half2* hs = reinterpret_cast<const __half2*>(&rs);
    float4 bv0 = *reinterpret_cast<const float4*>(bias + l * 8);
    float4 bv1 = *reinterpret_cast<const float4*>(bias + l * 8 + 4);
    float v[8];
    #pragma unroll
    for (int k = 0; k < 4; ++k) {
      float2 f = __half22float2(hs[k]);
      v[2 * k]     = fmaf(f.x, dii, acc[2 * k]);
      v[2 * k + 1] = fmaf(f.y, dii, acc[2 * k + 1]);
    }
    v[0] += bv0.x; v[1] += bv0.y; v[2] += bv0.z; v[3] += bv0.w;
    v[4] += bv1.x; v[5] += bv1.y; v[6] += bv1.z; v[7] += bv1.w;
    if (DO_RELU) {
      #pragma unroll
      for (int k = 0; k < 8; ++k) v[k] = fmaxf(v[k], 0.f);
    }
    if constexpr (std::is_same<TO, float>::value) {
      float4 o0 = make_float4(v[0], v[1], v[2], v[3]);
      float4 o1 = make_float4(v[4], v[5], v[6], v[7]);
      *reinterpret_cast<float4*>(out + (size_t)n * D + l * 8) = o0;
      *reinterpret_cast<float4*>(out + (size_t)n * D + l * 8 + 4) = o1;
    } else {
      uint4 pk;
      __half2 q0 = __floats2half2_rn(v[0], v[1]);
      __half2 q1 = __floats2half2_rn(v[2], v[3]);
      __half2 q2 = __floats2half2_rn(v[4], v[5]);
      __half2 q3 = __floats2half2_rn(v[6], v[7]);
      pk.x = *reinterpret_cast<unsigned int*>(&q0);
      pk.y = *reinterpret_cast<unsigned int*>(&q1);
      pk.z = *reinterpret_cast<unsigned int*>(&q2);
      pk.w = *reinterpret_cast<unsigned int*>(&q3);
      *reinterpret_cast<uint4*>((__half*)out + (size_t)n * D + l * 8) = pk;
    }
  }
}

// ---- launch ---------------------------------------------------------------

extern "C" void kernel_launch(void* const* d_in, const int* in_sizes, int n_in,
                              void* d_out, int out_size, void* d_ws, size_t ws_size,
                              hipStream_t stream) {
  const float* x  = (const float*)d_in[0];
  const int* edge = (const int*)d_in[1];
  const float* W1 = (const float*)d_in[2];
  const float* b1 = (const float*)d_in[3];
  const float* W2 = (const float*)d_in[4];
  const float* b2 = (const float*)d_in[5];
  const int N = in_sizes[0] / D;   // 50000
  const int E = in_sizes[1] / 2;   // 1.6M
  const int* srcp = edge;
  const int* dstp = edge + E;
  float* out = (float*)d_out;

  const int NP = (N + 1023) & ~1023;
  const int SB = NP / 1024;
  const int CH = (E + NI - 1) / NI;
  const int NRB = (N + NR - 1) / NR;

  auto align = [](size_t v) { return (v + 255) & ~(size_t)255; };
  char* ws = (char*)d_ws;
  size_t o = 0;
  int*   deg     = (int*)(ws + o);             o += align((size_t)NP * 4);
  int*   bsum    = (int*)(ws + o);             o += align((size_t)SB * 4);
  int*   offsets = (int*)(ws + o);             o += align((size_t)(N + 1) * 4);
  float* dinv    = (float*)(ws + o);           o += align((size_t)N * 4);
  unsigned short* c = (unsigned short*)(ws + o); o += align((size_t)NI * N * 2);  // 12.8MB
  unsigned int* csr = (unsigned int*)(ws + o); o += align((size_t)E * 4);
  __half* Hh     = (__half*)(ws + o);          o += align((size_t)N * D * 2);
  __half* h1h    = (__half*)(ws + o);          o += align((size_t)N * D * 2);
  __half* Wt1    = (__half*)(ws + o);          o += align((size_t)D * D * 2);
  __half* Wt2    = (__half*)(ws + o);          o += align((size_t)D * D * 2);

  int gemm_blocks = (N + 63) / 64;
  int agg_blocks  = (N + 3) / 4;

  // prep + CSR build — zero global atomics
  hipMemsetAsync(deg, 0, (size_t)NP * 4, stream);
  wprep_kernel<<<2, 256, 0, stream>>>(W1, W2, Wt1, Wt2);
  histA_kernel<<<dim3(NI, NRB), 1024, 0, stream>>>(dstp, c, E, N, CH);
  histB_kernel<<<(N + 255) / 256, 256, 0, stream>>>(c, deg, N);
  bsum_kernel<<<SB, 256, 0, stream>>>(deg, bsum);
  scan_kernel<<<SB, 256, 0, stream>>>(deg, bsum, offsets, dinv, N, E);
  placeC_kernel<<<dim3(NI, NRB), 1024, 0, stream>>>(srcp, dstp, c, offsets, dinv, csr, E, N, CH);

  // layer 1: h1 = relu(A @ (x@W1) + b1)   (fp16 intermediates, MFMA gemm)
  gemm_mfma_kernel<float><<<gemm_blocks, 256, 0, stream>>>(x, Wt1, Hh, N);
  agg_kernel<1, __half><<<agg_blocks, 256, 0, stream>>>(Hh, offsets, csr, dinv, b1, h1h, N);

  // layer 2: z = A @ (h1@W2) + b2 -> f32 d_out
  gemm_mfma_kernel<__half><<<gemm_blocks, 256, 0, stream>>>(h1h, Wt2, Hh, N);
  agg_kernel<0, float><<<agg_blocks, 256, 0, stream>>>(Hh, offsets, csr, dinv, b2, out, N);
}